// Round 1
// baseline (79.178 us; speedup 1.0000x reference)
//
#include <hip/hip_runtime.h>

#define MARGIN 0.3f
#define INF_BITS 0x7f800000

typedef __attribute__((ext_vector_type(8))) short bf16x8;
typedef __attribute__((ext_vector_type(4))) float f32x4;

__device__ inline unsigned short f2bf(float x) {
    unsigned int u = __float_as_uint(x);
    unsigned int r = (u + 0x7fffu + ((u >> 16) & 1u)) >> 16;
    return (unsigned short)r;
}

__device__ inline void gload16(const unsigned short* g, unsigned short* l) {
    __builtin_amdgcn_global_load_lds(
        (const __attribute__((address_space(1))) void*)g,
        (__attribute__((address_space(3))) void*)l, 16, 0, 0);
}

// ---------------------------------------------------------------------------
// Kernel 1: fp32 -> bf16 cast + per-row squared norms. One block per row.
// ---------------------------------------------------------------------------
__global__ void __launch_bounds__(256) prep_kernel(
    const float* __restrict__ in, unsigned short* __restrict__ bf,
    float* __restrict__ norms)
{
    const int row = blockIdx.x;
    const size_t base = (size_t)row * 1024;
    const float4 v = ((const float4*)(in + base))[threadIdx.x];
    float s = v.x * v.x + v.y * v.y + v.z * v.z + v.w * v.w;
    ushort4 o;
    o.x = f2bf(v.x); o.y = f2bf(v.y); o.z = f2bf(v.z); o.w = f2bf(v.w);
    ((ushort4*)(bf + base))[threadIdx.x] = o;
    #pragma unroll
    for (int off = 32; off > 0; off >>= 1) s += __shfl_down(s, off);
    __shared__ float wsum[4];
    if ((threadIdx.x & 63) == 0) wsum[threadIdx.x >> 6] = s;
    __syncthreads();
    if (threadIdx.x == 0) norms[row] = wsum[0] + wsum[1] + wsum[2] + wsum[3];
}

// ---------------------------------------------------------------------------
// Kernel 2: init the 4x4096 int-punned float reduction arrays.
// layout: [0:4096) rgb_ap = 0.0, [4096:8192) rgb_an = +inf,
//         [8192:12288) ir_ap = 0.0, [12288:16384) ir_an = +inf
// ---------------------------------------------------------------------------
__global__ void __launch_bounds__(256) init_kernel(int* __restrict__ red) {
    int i = blockIdx.x * 256 + threadIdx.x;   // 0..16383
    red[i] = ((i >> 12) & 1) ? INF_BITS : 0;
}

// ---------------------------------------------------------------------------
// Kernel 3: 128x128-tile bf16 MFMA GEMM (A = rgb, B^T input = ir), fused
// distance + masked row/col max/min epilogue with LDS + global atomics.
// ---------------------------------------------------------------------------
__global__ void __launch_bounds__(256) dist_kernel(
    const unsigned short* __restrict__ Abf, const unsigned short* __restrict__ Bbf,
    const float* __restrict__ na, const float* __restrict__ nb,
    const int* __restrict__ tgt,
    int* __restrict__ g_rgb_ap, int* __restrict__ g_rgb_an,
    int* __restrict__ g_ir_ap, int* __restrict__ g_ir_an)
{
    __shared__ unsigned short As[128 * 32];
    __shared__ unsigned short Bs[128 * 32];
    __shared__ int redRM[128], redRm[128], redCM[128], redCm[128];

    const int tid  = threadIdx.x;
    const int lane = tid & 63;
    const int wid  = tid >> 6;
    const int wrow = wid >> 1, wcol = wid & 1;
    const int brow = blockIdx.y, bcol = blockIdx.x;

    if (tid < 128) {
        redRM[tid] = 0; redRm[tid] = INF_BITS;
        redCM[tid] = 0; redCm[tid] = INF_BITS;
    }

    f32x4 acc[4][4];
    const f32x4 zero = {0.f, 0.f, 0.f, 0.f};
    #pragma unroll
    for (int m = 0; m < 4; ++m)
        #pragma unroll
        for (int n = 0; n < 4; ++n)
            acc[m][n] = zero;

    // staging: 512 chunks of 16B per tile (A and B each), 2 issues/thread each
    const int c0 = tid, c1 = 256 + tid;
    const int r0 = c0 >> 2, e0 = (c0 & 3) * 8;
    const int r1 = c1 >> 2, e1 = (c1 & 3) * 8;
    const unsigned short* ga0 = Abf + (size_t)(brow * 128 + r0) * 1024 + e0;
    const unsigned short* ga1 = Abf + (size_t)(brow * 128 + r1) * 1024 + e1;
    const unsigned short* gb0 = Bbf + (size_t)(bcol * 128 + r0) * 1024 + e0;
    const unsigned short* gb1 = Bbf + (size_t)(bcol * 128 + r1) * 1024 + e1;
    unsigned short* la0 = &As[c0 * 8];
    unsigned short* la1 = &As[c1 * 8];
    unsigned short* lb0 = &Bs[c0 * 8];
    unsigned short* lb1 = &Bs[c1 * 8];

    const int kofs = (lane >> 4) * 8;
    const int rsel = lane & 15;

    for (int kk = 0; kk < 1024; kk += 32) {
        __syncthreads();                 // previous iteration's ds_reads done
        gload16(ga0 + kk, la0);
        gload16(ga1 + kk, la1);
        gload16(gb0 + kk, lb0);
        gload16(gb1 + kk, lb1);
        __syncthreads();                 // compiler drains vmcnt before barrier

        bf16x8 af[4], bv[4];
        #pragma unroll
        for (int m = 0; m < 4; ++m)
            af[m] = *(const bf16x8*)&As[(wrow * 64 + m * 16 + rsel) * 32 + kofs];
        #pragma unroll
        for (int n = 0; n < 4; ++n)
            bv[n] = *(const bf16x8*)&Bs[(wcol * 64 + n * 16 + rsel) * 32 + kofs];
        #pragma unroll
        for (int m = 0; m < 4; ++m)
            #pragma unroll
            for (int n = 0; n < 4; ++n)
                acc[m][n] = __builtin_amdgcn_mfma_f32_16x16x32_bf16(
                    af[m], bv[n], acc[m][n], 0, 0, 0);
    }

    // ---------------- fused epilogue ----------------
    // C fragment mapping (m89): col = lane&15, row = (lane>>4)*4 + r
    // match(i,j) = tgt[j] == tgt[4096+i]   (reference's transposed label quirk)
    const float INF = __int_as_float(INF_BITS);

    int jg[4], ltcol[4];
    float nbv[4];
    #pragma unroll
    for (int n = 0; n < 4; ++n) {
        jg[n] = bcol * 128 + wcol * 64 + n * 16 + rsel;
        ltcol[n] = tgt[jg[n]];
        nbv[n] = nb[jg[n]];
    }

    float cmax[4] = {0.f, 0.f, 0.f, 0.f};
    float cmin[4] = {INF, INF, INF, INF};

    #pragma unroll
    for (int m = 0; m < 4; ++m) {
        #pragma unroll
        for (int r = 0; r < 4; ++r) {
            const int lrow = wrow * 64 + m * 16 + (lane >> 4) * 4 + r;
            const int ig = brow * 128 + lrow;
            const int lt = tgt[4096 + ig];
            const float nav = na[ig];
            float rx = 0.f, rn = INF;
            #pragma unroll
            for (int n = 0; n < 4; ++n) {
                float sq = nav + nbv[n] - 2.0f * acc[m][n][r];
                float d = sqrtf(fmaxf(sq, 1e-12f));
                bool match = (ltcol[n] == lt);
                rx = match ? fmaxf(rx, d) : rx;
                rn = match ? rn : fminf(rn, d);
                cmax[n] = match ? fmaxf(cmax[n], d) : cmax[n];
                cmin[n] = match ? cmin[n] : fminf(cmin[n], d);
            }
            atomicMax(&redRM[lrow], __float_as_int(rx));
            atomicMin(&redRm[lrow], __float_as_int(rn));
        }
    }
    #pragma unroll
    for (int n = 0; n < 4; ++n) {
        const int lcol = wcol * 64 + n * 16 + rsel;
        atomicMax(&redCM[lcol], __float_as_int(cmax[n]));
        atomicMin(&redCm[lcol], __float_as_int(cmin[n]));
    }
    __syncthreads();
    if (tid < 128) {
        atomicMax(&g_rgb_ap[brow * 128 + tid], redRM[tid]);
        atomicMin(&g_rgb_an[brow * 128 + tid], redRm[tid]);
        atomicMax(&g_ir_ap[bcol * 128 + tid], redCM[tid]);
        atomicMin(&g_ir_an[bcol * 128 + tid], redCm[tid]);
    }
}

// ---------------------------------------------------------------------------
// Kernel 4: final loss = mean(relu(M-(rgb_an-rgb_ap))) + mean(relu(M-(ir_an-ir_ap)))
// Single block so no cross-block sync needed.
// ---------------------------------------------------------------------------
__global__ void __launch_bounds__(256) loss_kernel(
    const int* __restrict__ red, float* __restrict__ out)
{
    float s = 0.f;
    for (int i = threadIdx.x; i < 4096; i += 256) {
        float ap  = __int_as_float(red[i]);
        float an  = __int_as_float(red[4096 + i]);
        s += fmaxf(0.f, MARGIN - (an - ap));
        float ap2 = __int_as_float(red[8192 + i]);
        float an2 = __int_as_float(red[12288 + i]);
        s += fmaxf(0.f, MARGIN - (an2 - ap2));
    }
    #pragma unroll
    for (int off = 32; off > 0; off >>= 1) s += __shfl_down(s, off);
    __shared__ float wsum[4];
    if ((threadIdx.x & 63) == 0) wsum[threadIdx.x >> 6] = s;
    __syncthreads();
    if (threadIdx.x == 0) out[0] = (wsum[0] + wsum[1] + wsum[2] + wsum[3]) / 4096.0f;
}

// ---------------------------------------------------------------------------
extern "C" void kernel_launch(void* const* d_in, const int* in_sizes, int n_in,
                              void* d_out, int out_size, void* d_ws, size_t ws_size,
                              hipStream_t stream) {
    const float* input = (const float*)d_in[0];
    const int* tgt = (const int*)d_in[1];
    float* out = (float*)d_out;

    // workspace layout: bf16 copy (16 MB) | norms (32 KB) | red arrays (64 KB)
    unsigned short* bf = (unsigned short*)d_ws;
    float* norms = (float*)(bf + (size_t)8192 * 1024);
    int* red = (int*)(norms + 8192);

    prep_kernel<<<8192, 256, 0, stream>>>(input, bf, norms);
    init_kernel<<<64, 256, 0, stream>>>(red);
    dist_kernel<<<dim3(32, 32), 256, 0, stream>>>(
        bf, bf + (size_t)4096 * 1024, norms, norms + 4096, tgt,
        red, red + 4096, red + 8192, red + 12288);
    loss_kernel<<<1, 256, 0, stream>>>(red, out);
}

// Round 2
// 71.714 us; speedup vs baseline: 1.1041x; 1.1041x over previous
//
#include <hip/hip_runtime.h>

#define MARGIN 0.3f
#define INF_BITS 0x7f800000

typedef __attribute__((ext_vector_type(8))) short bf16x8;
typedef __attribute__((ext_vector_type(4))) float f32x4;

__device__ inline unsigned short f2bf(float x) {
    unsigned int u = __float_as_uint(x);
    unsigned int r = (u + 0x7fffu + ((u >> 16) & 1u)) >> 16;
    return (unsigned short)r;
}

__device__ __forceinline__ void gload16(const unsigned short* g, char* l) {
    __builtin_amdgcn_global_load_lds(
        (const __attribute__((address_space(1))) void*)g,
        (__attribute__((address_space(3))) void*)l, 16, 0, 0);
}

// stage one 128x64 half-tile: this thread's 2 chunks (rows r0 and r0+64)
__device__ __forceinline__ void stage_half(const unsigned short* g, char* l) {
    gload16(g, l);                 // row r0
    gload16(g + 65536, l + 8192);  // row r0+64 (64*1024 elems further)
}

// ---------------------------------------------------------------------------
// Kernel 1: fp32 -> bf16 cast + per-row squared norms. One block per row.
// ---------------------------------------------------------------------------
__global__ void __launch_bounds__(256) prep_kernel(
    const float* __restrict__ in, unsigned short* __restrict__ bf,
    float* __restrict__ norms)
{
    const int row = blockIdx.x;
    const size_t base = (size_t)row * 1024;
    const float4 v = ((const float4*)(in + base))[threadIdx.x];
    float s = v.x * v.x + v.y * v.y + v.z * v.z + v.w * v.w;
    ushort4 o;
    o.x = f2bf(v.x); o.y = f2bf(v.y); o.z = f2bf(v.z); o.w = f2bf(v.w);
    ((ushort4*)(bf + base))[threadIdx.x] = o;
    #pragma unroll
    for (int off = 32; off > 0; off >>= 1) s += __shfl_down(s, off);
    __shared__ float wsum[4];
    if ((threadIdx.x & 63) == 0) wsum[threadIdx.x >> 6] = s;
    __syncthreads();
    if (threadIdx.x == 0) norms[row] = wsum[0] + wsum[1] + wsum[2] + wsum[3];
}

// ---------------------------------------------------------------------------
// Kernel 2: init the 4x4096 int-punned float reduction arrays.
// ---------------------------------------------------------------------------
__global__ void __launch_bounds__(256) init_kernel(int* __restrict__ red) {
    int i = blockIdx.x * 256 + threadIdx.x;   // 0..16383
    red[i] = ((i >> 12) & 1) ? INF_BITS : 0;
}

// ---------------------------------------------------------------------------
// Kernel 3: 256x256-tile, 8-phase bf16 MFMA GEMM + fused masked reductions.
// 512 threads (8 waves, 2Mx4N). BK=64, double-buffered 128KB LDS, XOR-swizzle.
// ---------------------------------------------------------------------------
#define VM_WAIT(n) asm volatile("s_waitcnt vmcnt(" #n ")" ::: "memory")

// LDS layout (dynamic): buffer b at b*65536:
//   Ah0 @ +0, Ah1 @ +16384, Bh0 @ +32768, Bh1 @ +49152  (each 128x64 bf16=16KB)
// red arrays at +131072 (4 x 256 ints)
#define STAGE_A(h, kt, b) \
    stage_half(pA + (h)*131072 + (((kt) & 15) << 6), lds + (b)*65536 + (h)*16384 + tid*16)
#define STAGE_B(h, kt, b) \
    stage_half(pB + (h)*131072 + (((kt) & 15) << 6), lds + (b)*65536 + 32768 + (h)*16384 + tid*16)

// One phase: read A-frags for quadrant qq (and all B-frags if qq==0) from
// buffer bc, issue one half-tile stage, barrier, lgkmcnt(0), 16 MFMA, barrier.
#define PHASE(qq, bc, STAGE_STMT, WAIT_STMT)                                     \
  {                                                                              \
    const char* ab = lds + (bc) * 65536 + aoff + (2 * (qq)) * 2048;              \
    bf16x8 a0k0 = *(const bf16x8*)(ab + swz0);                                   \
    bf16x8 a0k1 = *(const bf16x8*)(ab + swz1);                                   \
    bf16x8 a1k0 = *(const bf16x8*)(ab + 2048 + swz0);                            \
    bf16x8 a1k1 = *(const bf16x8*)(ab + 2048 + swz1);                            \
    if ((qq) == 0) {                                                             \
      const char* bb = lds + (bc) * 65536 + boff;                                \
      _Pragma("unroll")                                                          \
      for (int n = 0; n < 4; ++n) {                                              \
        bk0[n] = *(const bf16x8*)(bb + n * 2048 + swz0);                         \
        bk1[n] = *(const bf16x8*)(bb + n * 2048 + swz1);                         \
      }                                                                          \
    }                                                                            \
    STAGE_STMT;                                                                  \
    __builtin_amdgcn_s_barrier();                                                \
    asm volatile("s_waitcnt lgkmcnt(0)" ::: "memory");                           \
    __builtin_amdgcn_sched_barrier(0);                                           \
    __builtin_amdgcn_s_setprio(1);                                               \
    _Pragma("unroll")                                                            \
    for (int n = 0; n < 4; ++n) {                                                \
      acc[2*(qq)][n]   = __builtin_amdgcn_mfma_f32_16x16x32_bf16(a0k0, bk0[n], acc[2*(qq)][n], 0, 0, 0);   \
      acc[2*(qq)][n]   = __builtin_amdgcn_mfma_f32_16x16x32_bf16(a0k1, bk1[n], acc[2*(qq)][n], 0, 0, 0);   \
      acc[2*(qq)+1][n] = __builtin_amdgcn_mfma_f32_16x16x32_bf16(a1k0, bk0[n], acc[2*(qq)+1][n], 0, 0, 0); \
      acc[2*(qq)+1][n] = __builtin_amdgcn_mfma_f32_16x16x32_bf16(a1k1, bk1[n], acc[2*(qq)+1][n], 0, 0, 0); \
    }                                                                            \
    __builtin_amdgcn_s_setprio(0);                                               \
    WAIT_STMT;                                                                   \
    __builtin_amdgcn_s_barrier();                                                \
  }

__global__ void __launch_bounds__(512, 2) dist_kernel(
    const unsigned short* __restrict__ Abf, const unsigned short* __restrict__ Bbf,
    const float* __restrict__ na, const float* __restrict__ nb,
    const int* __restrict__ tgt,
    int* __restrict__ g_rgb_ap, int* __restrict__ g_rgb_an,
    int* __restrict__ g_ir_ap, int* __restrict__ g_ir_an)
{
    extern __shared__ char lds[];

    const int tid  = threadIdx.x;
    const int lane = tid & 63;
    const int wid  = tid >> 6;          // 0..7
    const int wr   = wid >> 2;          // 0..1  (M)
    const int wc   = wid & 3;           // 0..3  (N)
    const int brow = blockIdx.y, bcol = blockIdx.x;
    const int l4 = lane >> 4, rsel = lane & 15;

    // --- staging addresses (chunk = 16B; thread handles chunks tid, tid+512) ---
    // LDS is written linearly; the XOR swizzle is applied to the GLOBAL source
    // column so that LDS position (r, cs) holds global column cs^((r&7)<<4).
    const int r0 = tid >> 3;                          // 0..63
    const int cs = (tid & 7) << 4;                    // LDS chunk byte pos
    const int c0 = (cs ^ ((r0 & 7) << 4)) >> 1;       // global col (elems)
    const unsigned short* pA = Abf + (size_t)(brow * 256 + r0) * 1024 + c0;
    const unsigned short* pB = Bbf + (size_t)(bcol * 256 + r0) * 1024 + c0;

    // --- ds_read offsets (swizzled to match) ---
    const int swz0 = ((l4 ^ (rsel & 7)) << 4);        // ks=0 chunk
    const int swz1 = (((4 + l4) ^ (rsel & 7)) << 4);  // ks=1 chunk
    const int aoff = wr * 16384 + rsel * 128;
    const int boff = 32768 + (wc >> 1) * 16384 + (wc & 1) * 8192 + rsel * 128;

    f32x4 acc[8][4];
    const f32x4 zero = {0.f, 0.f, 0.f, 0.f};
    #pragma unroll
    for (int m = 0; m < 8; ++m)
        #pragma unroll
        for (int n = 0; n < 4; ++n)
            acc[m][n] = zero;

    bf16x8 bk0[4], bk1[4];

    // --- prologue: K0 full -> buf0, K1 B-halves -> buf1 ---
    STAGE_A(0, 0, 0); STAGE_A(1, 0, 0);
    STAGE_B(0, 0, 0); STAGE_B(1, 0, 0);
    STAGE_B(0, 1, 1); STAGE_B(1, 1, 1);
    asm volatile("s_waitcnt vmcnt(0)" ::: "memory");
    __builtin_amdgcn_s_barrier();

    // --- main loop: 16 K-tiles, 2 per iteration, 8 phases ---
    for (int i = 0; i < 8; ++i) {
        const int t = 2 * i;
        PHASE(0, 0, STAGE_A(0, t + 1, 1), );
        PHASE(1, 0, STAGE_A(1, t + 1, 1), );
        PHASE(2, 0, STAGE_B(0, t + 2, 0), );
        PHASE(3, 0, STAGE_B(1, t + 2, 0), VM_WAIT(4));
        PHASE(0, 1, STAGE_A(0, t + 2, 0), );
        PHASE(1, 1, STAGE_A(1, t + 2, 0), );
        PHASE(2, 1, STAGE_B(0, t + 3, 1), );
        PHASE(3, 1, STAGE_B(1, t + 3, 1), VM_WAIT(4));
    }

    // --- fused epilogue ---
    asm volatile("s_waitcnt vmcnt(0)" ::: "memory");
    __syncthreads();

    int* redRM = (int*)(lds + 131072);
    int* redRm = redRM + 256;
    int* redCM = redRM + 512;
    int* redCm = redRM + 768;
    if (tid < 256) {
        redRM[tid] = 0; redRm[tid] = INF_BITS;
        redCM[tid] = 0; redCm[tid] = INF_BITS;
    }
    __syncthreads();

    const float INF = __int_as_float(INF_BITS);
    int jg[4], ltc[4];
    float nbv[4];
    #pragma unroll
    for (int n = 0; n < 4; ++n) {
        jg[n] = bcol * 256 + wc * 64 + n * 16 + rsel;
        ltc[n] = tgt[jg[n]];
        nbv[n] = nb[jg[n]];
    }

    float cmax[4] = {0.f, 0.f, 0.f, 0.f};
    float cmin[4] = {INF, INF, INF, INF};

    #pragma unroll
    for (int m = 0; m < 8; ++m) {
        #pragma unroll
        for (int r = 0; r < 4; ++r) {
            const int lrow = wr * 128 + m * 16 + l4 * 4 + r;
            const int ig = brow * 256 + lrow;
            const int lt = tgt[4096 + ig];
            const float nav = na[ig];
            float rx = 0.f, rn = INF;
            #pragma unroll
            for (int n = 0; n < 4; ++n) {
                float sq = nav + nbv[n] - 2.0f * acc[m][n][r];
                float d = sqrtf(fmaxf(sq, 1e-12f));
                bool match = (ltc[n] == lt);
                rx = match ? fmaxf(rx, d) : rx;
                rn = match ? rn : fminf(rn, d);
                cmax[n] = match ? fmaxf(cmax[n], d) : cmax[n];
                cmin[n] = match ? cmin[n] : fminf(cmin[n], d);
            }
            // reduce across the 16-lane rsel group (same row, different cols)
            #pragma unroll
            for (int s = 1; s < 16; s <<= 1) {
                rx = fmaxf(rx, __shfl_xor(rx, s));
                rn = fminf(rn, __shfl_xor(rn, s));
            }
            if (rsel == 0) {
                atomicMax(&redRM[lrow], __float_as_int(rx));
                atomicMin(&redRm[lrow], __float_as_int(rn));
            }
        }
    }
    #pragma unroll
    for (int n = 0; n < 4; ++n) {
        float cx = cmax[n], cn = cmin[n];
        cx = fmaxf(cx, __shfl_xor(cx, 16)); cx = fmaxf(cx, __shfl_xor(cx, 32));
        cn = fminf(cn, __shfl_xor(cn, 16)); cn = fminf(cn, __shfl_xor(cn, 32));
        if (l4 == 0) {
            const int lcol = wc * 64 + n * 16 + rsel;
            atomicMax(&redCM[lcol], __float_as_int(cx));
            atomicMin(&redCm[lcol], __float_as_int(cn));
        }
    }
    __syncthreads();
    if (tid < 256) {
        atomicMax(&g_rgb_ap[brow * 256 + tid], redRM[tid]);
        atomicMin(&g_rgb_an[brow * 256 + tid], redRm[tid]);
        atomicMax(&g_ir_ap[bcol * 256 + tid], redCM[tid]);
        atomicMin(&g_ir_an[bcol * 256 + tid], redCm[tid]);
    }
}

// ---------------------------------------------------------------------------
// Kernel 4: final loss.
// ---------------------------------------------------------------------------
__global__ void __launch_bounds__(256) loss_kernel(
    const int* __restrict__ red, float* __restrict__ out)
{
    float s = 0.f;
    for (int i = threadIdx.x; i < 4096; i += 256) {
        float ap  = __int_as_float(red[i]);
        float an  = __int_as_float(red[4096 + i]);
        s += fmaxf(0.f, MARGIN - (an - ap));
        float ap2 = __int_as_float(red[8192 + i]);
        float an2 = __int_as_float(red[12288 + i]);
        s += fmaxf(0.f, MARGIN - (an2 - ap2));
    }
    #pragma unroll
    for (int off = 32; off > 0; off >>= 1) s += __shfl_down(s, off);
    __shared__ float wsum[4];
    if ((threadIdx.x & 63) == 0) wsum[threadIdx.x >> 6] = s;
    __syncthreads();
    if (threadIdx.x == 0) out[0] = (wsum[0] + wsum[1] + wsum[2] + wsum[3]) / 4096.0f;
}

// ---------------------------------------------------------------------------
extern "C" void kernel_launch(void* const* d_in, const int* in_sizes, int n_in,
                              void* d_out, int out_size, void* d_ws, size_t ws_size,
                              hipStream_t stream) {
    (void)in_sizes; (void)n_in; (void)out_size; (void)ws_size;
    const float* input = (const float*)d_in[0];
    const int* tgt = (const int*)d_in[1];
    float* out = (float*)d_out;

    // workspace: bf16 copy (16 MB) | norms (32 KB) | red arrays (64 KB)
    unsigned short* bf = (unsigned short*)d_ws;
    float* norms = (float*)(bf + (size_t)8192 * 1024);
    int* red = (int*)(norms + 8192);

    static int lds_set = 0;
    if (!lds_set) {
        hipFuncSetAttribute((const void*)dist_kernel,
                            hipFuncAttributeMaxDynamicSharedMemorySize, 135168);
        lds_set = 1;
    }

    prep_kernel<<<8192, 256, 0, stream>>>(input, bf, norms);
    init_kernel<<<64, 256, 0, stream>>>(red);
    dist_kernel<<<dim3(16, 16), 512, 135168, stream>>>(
        bf, bf + (size_t)4096 * 1024, norms, norms + 4096, tgt,
        red, red + 4096, red + 8192, red + 12288);
    loss_kernel<<<1, 256, 0, stream>>>(red, out);
}

// Round 3
// 47.529 us; speedup vs baseline: 1.6659x; 1.5088x over previous
//
#include <hip/hip_runtime.h>

#define MARGIN 0.3f
#define INF_BITS 0x7f800000
#define NINF_BITS 0xff800000

typedef __attribute__((ext_vector_type(8))) short bf16x8;
typedef __attribute__((ext_vector_type(4))) float f32x4;

__device__ inline unsigned short f2bf(float x) {
    unsigned int u = __float_as_uint(x);
    unsigned int r = (u + 0x7fffu + ((u >> 16) & 1u)) >> 16;
    return (unsigned short)r;
}

__device__ __forceinline__ void gload16(const unsigned short* g, char* l) {
    __builtin_amdgcn_global_load_lds(
        (const __attribute__((address_space(1))) void*)g,
        (__attribute__((address_space(3))) void*)l, 16, 0, 0);
}

// stage one 128x64 half-tile: this thread's 2 chunks (rows r0 and r0+64)
__device__ __forceinline__ void stage_half(const unsigned short* g, char* l) {
    gload16(g, l);                 // row r0
    gload16(g + 65536, l + 8192);  // row r0+64
}

// ---------------------------------------------------------------------------
// Kernel 1: fp32 -> bf16 cast + per-row norms (wave per row) + red-array init.
// ---------------------------------------------------------------------------
__global__ void __launch_bounds__(256) prep_kernel(
    const float* __restrict__ in, unsigned short* __restrict__ bf,
    float* __restrict__ norms, int* __restrict__ red)
{
    const int wid = threadIdx.x >> 6, lane = threadIdx.x & 63;
    const int row = blockIdx.x * 4 + wid;
    const size_t base = (size_t)row * 1024;
    float s = 0.f;
    #pragma unroll
    for (int k = 0; k < 4; ++k) {
        const float4 v = ((const float4*)(in + base))[lane + 64 * k];
        s += v.x * v.x + v.y * v.y + v.z * v.z + v.w * v.w;
        ushort4 o;
        o.x = f2bf(v.x); o.y = f2bf(v.y); o.z = f2bf(v.z); o.w = f2bf(v.w);
        ((ushort4*)(bf + base))[lane + 64 * k] = o;
    }
    #pragma unroll
    for (int off = 32; off > 0; off >>= 1) s += __shfl_down(s, off);
    if (lane == 0) norms[row] = s;
    if (blockIdx.x < 64) {
        int i = blockIdx.x * 256 + threadIdx.x;   // 0..16383
        red[i] = ((i >> 12) & 1) ? INF_BITS : 0;
    }
}

// ---------------------------------------------------------------------------
// Kernel 2: 256x256-tile, 8-phase bf16 MFMA GEMM + fused masked reductions.
// ---------------------------------------------------------------------------
#define VM_WAIT(n) asm volatile("s_waitcnt vmcnt(" #n ")" ::: "memory")

#define STAGE_A(h, kt, b) \
    stage_half(pA + (h)*131072 + (((kt) & 15) << 6), lds + (b)*65536 + (h)*16384 + tid*16)
#define STAGE_B(h, kt, b) \
    stage_half(pB + (h)*131072 + (((kt) & 15) << 6), lds + (b)*65536 + 32768 + (h)*16384 + tid*16)

#define PHASE(qq, bc, STAGE_STMT, WAIT_STMT)                                     \
  {                                                                              \
    const char* ab = lds + (bc) * 65536 + aoff + (2 * (qq)) * 2048;              \
    bf16x8 a0k0 = *(const bf16x8*)(ab + swz0);                                   \
    bf16x8 a0k1 = *(const bf16x8*)(ab + swz1);                                   \
    bf16x8 a1k0 = *(const bf16x8*)(ab + 2048 + swz0);                            \
    bf16x8 a1k1 = *(const bf16x8*)(ab + 2048 + swz1);                            \
    if ((qq) == 0) {                                                             \
      const char* bb = lds + (bc) * 65536 + boff;                                \
      _Pragma("unroll")                                                          \
      for (int n = 0; n < 4; ++n) {                                              \
        bk0[n] = *(const bf16x8*)(bb + n * 2048 + swz0);                         \
        bk1[n] = *(const bf16x8*)(bb + n * 2048 + swz1);                         \
      }                                                                          \
    }                                                                            \
    STAGE_STMT;                                                                  \
    if ((qq) == 0) asm volatile("s_waitcnt lgkmcnt(8)" ::: "memory");            \
    __builtin_amdgcn_s_barrier();                                                \
    asm volatile("s_waitcnt lgkmcnt(0)" ::: "memory");                           \
    __builtin_amdgcn_sched_barrier(0);                                           \
    __builtin_amdgcn_s_setprio(1);                                               \
    _Pragma("unroll")                                                            \
    for (int n = 0; n < 4; ++n) {                                                \
      acc[2*(qq)][n]   = __builtin_amdgcn_mfma_f32_16x16x32_bf16(a0k0, bk0[n], acc[2*(qq)][n], 0, 0, 0);   \
      acc[2*(qq)+1][n] = __builtin_amdgcn_mfma_f32_16x16x32_bf16(a1k0, bk0[n], acc[2*(qq)+1][n], 0, 0, 0); \
    }                                                                            \
    _Pragma("unroll")                                                            \
    for (int n = 0; n < 4; ++n) {                                                \
      acc[2*(qq)][n]   = __builtin_amdgcn_mfma_f32_16x16x32_bf16(a0k1, bk1[n], acc[2*(qq)][n], 0, 0, 0);   \
      acc[2*(qq)+1][n] = __builtin_amdgcn_mfma_f32_16x16x32_bf16(a1k1, bk1[n], acc[2*(qq)+1][n], 0, 0, 0); \
    }                                                                            \
    __builtin_amdgcn_s_setprio(0);                                               \
    WAIT_STMT;                                                                   \
    __builtin_amdgcn_s_barrier();                                                \
  }

__global__ void __launch_bounds__(512, 2) dist_kernel(
    const unsigned short* __restrict__ Abf, const unsigned short* __restrict__ Bbf,
    const float* __restrict__ na, const float* __restrict__ nb,
    const int* __restrict__ tgt,
    int* __restrict__ g_rgb_ap, int* __restrict__ g_rgb_an,
    int* __restrict__ g_ir_ap, int* __restrict__ g_ir_an)
{
    extern __shared__ char lds[];

    const int tid  = threadIdx.x;
    const int lane = tid & 63;
    const int wid  = tid >> 6;          // 0..7
    const int wr   = wid >> 2;          // 0..1  (M)
    const int wc   = wid & 3;           // 0..3  (N)
    const int l4 = lane >> 4, rsel = lane & 15;

    // XCD-bijective swizzle: each XCD gets a 4(brow) x 8(bcol) region.
    const int lin = blockIdx.y * 16 + blockIdx.x;
    const int xcd = lin & 7, idx = lin >> 3;
    const int brow = (xcd >> 1) * 4 + (idx >> 3);
    const int bcol = (xcd & 1) * 8 + (idx & 7);

    // staging addresses (swizzle on the GLOBAL source column; LDS linear)
    const int r0 = tid >> 3;
    const int cs = (tid & 7) << 4;
    const int c0 = (cs ^ ((r0 & 7) << 4)) >> 1;
    const unsigned short* pA = Abf + (size_t)(brow * 256 + r0) * 1024 + c0;
    const unsigned short* pB = Bbf + (size_t)(bcol * 256 + r0) * 1024 + c0;

    // ds_read offsets (swizzled to match)
    const int swz0 = ((l4 ^ (rsel & 7)) << 4);
    const int swz1 = (((4 + l4) ^ (rsel & 7)) << 4);
    const int aoff = wr * 16384 + rsel * 128;
    const int boff = 32768 + (wc >> 1) * 16384 + (wc & 1) * 8192 + rsel * 128;

    f32x4 acc[8][4];
    const f32x4 zero = {0.f, 0.f, 0.f, 0.f};
    #pragma unroll
    for (int m = 0; m < 8; ++m)
        #pragma unroll
        for (int n = 0; n < 4; ++n)
            acc[m][n] = zero;

    bf16x8 bk0[4], bk1[4];

    // prologue: K0 full -> buf0, K1 B-halves -> buf1; drain only K0
    STAGE_A(0, 0, 0); STAGE_A(1, 0, 0);
    STAGE_B(0, 0, 0); STAGE_B(1, 0, 0);
    STAGE_B(0, 1, 1); STAGE_B(1, 1, 1);
    VM_WAIT(4);
    __builtin_amdgcn_s_barrier();

    for (int i = 0; i < 8; ++i) {
        const int t = 2 * i;
        PHASE(0, 0, STAGE_A(0, t + 1, 1), );
        PHASE(1, 0, STAGE_A(1, t + 1, 1), );
        PHASE(2, 0, STAGE_B(0, t + 2, 0), );
        PHASE(3, 0, STAGE_B(1, t + 2, 0), VM_WAIT(4));
        PHASE(0, 1, STAGE_A(0, t + 2, 0), );
        PHASE(1, 1, STAGE_A(1, t + 2, 0), );
        PHASE(2, 1, STAGE_B(0, t + 3, 1), );
        PHASE(3, 1, STAGE_B(1, t + 3, 1), VM_WAIT(4));
    }

    // ---------------- fused epilogue (sq-space reductions) ----------------
    VM_WAIT(0);
    __syncthreads();

    // LDS partials (reuse GEMM buffers; all slots written exactly once):
    //   rowpair: [256 rows][64 (wc,rsel)] float2(max,min), stride 132 words
    //   colMax/colMin: [256 cols][9] float (slot wr*4+l4, +1 pad)
    char* rowbase = lds;                       // 256*528 = 135168 B
    float* colMax = (float*)(lds + 135168);    // 9216 B
    float* colMin = (float*)(lds + 144384);    // 9216 B

    const float NINF = __int_as_float((int)NINF_BITS);
    const float PINF = __int_as_float(INF_BITS);

    int jg[4], ltc[4];
    float nbv[4];
    #pragma unroll
    for (int n = 0; n < 4; ++n) {
        jg[n] = bcol * 256 + wc * 64 + n * 16 + rsel;
        ltc[n] = tgt[jg[n]];
        nbv[n] = nb[jg[n]];
    }

    float cmax[4] = {NINF, NINF, NINF, NINF};
    float cmin[4] = {PINF, PINF, PINF, PINF};

    #pragma unroll
    for (int m = 0; m < 8; ++m) {
        #pragma unroll
        for (int r = 0; r < 4; ++r) {
            const int lrow = wr * 128 + m * 16 + l4 * 4 + r;
            const int ig = brow * 256 + lrow;
            const int lt = tgt[4096 + ig];
            const float nav = na[ig];
            float rx = NINF, rn = PINF;
            #pragma unroll
            for (int n = 0; n < 4; ++n) {
                const float urow = __builtin_fmaf(-2.0f, acc[m][n][r], nbv[n]);
                const float ucol = __builtin_fmaf(-2.0f, acc[m][n][r], nav);
                const bool match = (ltc[n] == lt);
                rx = match ? fmaxf(rx, urow) : rx;
                rn = match ? rn : fminf(rn, urow);
                cmax[n] = match ? fmaxf(cmax[n], ucol) : cmax[n];
                cmin[n] = match ? cmin[n] : fminf(cmin[n], ucol);
            }
            float2* rp = (float2*)(rowbase + lrow * 528 + (wc * 16 + rsel) * 8);
            *rp = make_float2(rx, rn);
        }
    }
    #pragma unroll
    for (int n = 0; n < 4; ++n) {
        const int lcol = wc * 64 + n * 16 + rsel;
        colMax[lcol * 9 + wr * 4 + l4] = cmax[n];
        colMin[lcol * 9 + wr * 4 + l4] = cmin[n];
    }
    __syncthreads();

    if (tid < 256) {
        // row reduce: partials are (nb_j - 2dot); add na, clip, sqrt, atomic
        const int row = tid;
        const f32x4* rp = (const f32x4*)(rowbase + row * 528);
        float rmax = NINF, rmin = PINF;
        #pragma unroll 8
        for (int s = 0; s < 32; ++s) {
            const f32x4 v = rp[s];
            rmax = fmaxf(rmax, fmaxf(v[0], v[2]));
            rmin = fminf(rmin, fminf(v[1], v[3]));
        }
        const int ig = brow * 256 + row;
        const float nav = na[ig];
        const float ap = sqrtf(fmaxf(nav + rmax, 1e-12f));
        const float an = sqrtf(fmaxf(nav + rmin, 1e-12f));
        atomicMax(&g_rgb_ap[ig], __float_as_int(ap));
        atomicMin(&g_rgb_an[ig], __float_as_int(an));
    } else {
        // col reduce: partials are (na_i - 2dot); add nb, clip, sqrt, atomic
        const int col = tid & 255;
        float cm = NINF, cn = PINF;
        #pragma unroll
        for (int s = 0; s < 8; ++s) {
            cm = fmaxf(cm, colMax[col * 9 + s]);
            cn = fminf(cn, colMin[col * 9 + s]);
        }
        const int jgc = bcol * 256 + col;
        const float nbc = nb[jgc];
        const float ap = sqrtf(fmaxf(nbc + cm, 1e-12f));
        const float an = sqrtf(fmaxf(nbc + cn, 1e-12f));
        atomicMax(&g_ir_ap[jgc], __float_as_int(ap));
        atomicMin(&g_ir_an[jgc], __float_as_int(an));
    }
}

// ---------------------------------------------------------------------------
// Kernel 3: final loss (int4-vectorized single block).
// ---------------------------------------------------------------------------
__global__ void __launch_bounds__(256) loss_kernel(
    const int* __restrict__ red, float* __restrict__ out)
{
    float s = 0.f;
    const int t = threadIdx.x;
    #pragma unroll
    for (int k = 0; k < 4; ++k) {
        const int idx = k * 256 + t;             // int4 index, 0..1023
        const int4 ap  = ((const int4*)(red))[idx];
        const int4 an  = ((const int4*)(red + 4096))[idx];
        const int4 ap2 = ((const int4*)(red + 8192))[idx];
        const int4 an2 = ((const int4*)(red + 12288))[idx];
        s += fmaxf(0.f, MARGIN - (__int_as_float(an.x) - __int_as_float(ap.x)));
        s += fmaxf(0.f, MARGIN - (__int_as_float(an.y) - __int_as_float(ap.y)));
        s += fmaxf(0.f, MARGIN - (__int_as_float(an.z) - __int_as_float(ap.z)));
        s += fmaxf(0.f, MARGIN - (__int_as_float(an.w) - __int_as_float(ap.w)));
        s += fmaxf(0.f, MARGIN - (__int_as_float(an2.x) - __int_as_float(ap2.x)));
        s += fmaxf(0.f, MARGIN - (__int_as_float(an2.y) - __int_as_float(ap2.y)));
        s += fmaxf(0.f, MARGIN - (__int_as_float(an2.z) - __int_as_float(ap2.z)));
        s += fmaxf(0.f, MARGIN - (__int_as_float(an2.w) - __int_as_float(ap2.w)));
    }
    #pragma unroll
    for (int off = 32; off > 0; off >>= 1) s += __shfl_down(s, off);
    __shared__ float wsum[4];
    if ((threadIdx.x & 63) == 0) wsum[threadIdx.x >> 6] = s;
    __syncthreads();
    if (threadIdx.x == 0) out[0] = (wsum[0] + wsum[1] + wsum[2] + wsum[3]) / 4096.0f;
}

// ---------------------------------------------------------------------------
extern "C" void kernel_launch(void* const* d_in, const int* in_sizes, int n_in,
                              void* d_out, int out_size, void* d_ws, size_t ws_size,
                              hipStream_t stream) {
    (void)in_sizes; (void)n_in; (void)out_size; (void)ws_size;
    const float* input = (const float*)d_in[0];
    const int* tgt = (const int*)d_in[1];
    float* out = (float*)d_out;

    unsigned short* bf = (unsigned short*)d_ws;
    float* norms = (float*)(bf + (size_t)8192 * 1024);
    int* red = (int*)(norms + 8192);

    hipFuncSetAttribute((const void*)dist_kernel,
                        hipFuncAttributeMaxDynamicSharedMemorySize, 153600);

    prep_kernel<<<2048, 256, 0, stream>>>(input, bf, norms, red);
    dist_kernel<<<dim3(16, 16), 512, 153600, stream>>>(
        bf, bf + (size_t)4096 * 1024, norms, norms + 4096, tgt,
        red, red + 4096, red + 8192, red + 12288);
    loss_kernel<<<1, 256, 0, stream>>>(red, out);
}